// Round 3
// baseline (659.645 us; speedup 1.0000x reference)
//
#include <hip/hip_runtime.h>

// ---------------------------------------------------------------------------
// SparseLoRAMoE: out = (gate ⊙ (x @ A_flat^T)) @ Bflat * 0.5
//   N=16384 tokens, D=4096, E=8 experts, R=16, C=E*R=128, O=4096, TOP_K=2
// Round 3: g1f main loop made BARRIER-FREE and LDS-FREE.
//   R2 counters: g1f 188us, hbm 9.5%, Mfma 3.6%, VALU 18% -> latency-bound.
//   Cause: compiler drains vmcnt(0) at every __syncthreads -> prefetch dead.
//   Fix: each wave loads its MFMA fragments DIRECTLY from global (x fp32 ->
//   bf16 in-register; A_bf from L2), depth-1 register prefetch, no barriers
//   in the loop -> dependency-driven counted vmcnt keeps loads in flight.
// ---------------------------------------------------------------------------

#define NTOK   16384
#define DDIM   4096
#define NEXP   8
#define CDIM   128     // E*R
#define ODIM   4096

typedef float  f32x4  __attribute__((ext_vector_type(4)));
typedef __bf16 bf16x8 __attribute__((ext_vector_type(8)));

__device__ __forceinline__ unsigned short f2bf(float f) {
    union { float f; unsigned u; } v; v.f = f;
    unsigned r = v.u + 0x7FFFu + ((v.u >> 16) & 1u);   // RNE
    return (unsigned short)(r >> 16);
}

// ---------------------------------------------------------------------------
// prep: A [128,4096] fp32 -> bf16 (same layout); Bm [8,4096,16] fp32 ->
//       Bt [o=4096][c=128] bf16 (o-major, c contiguous)
// grid 4096 x 256
// ---------------------------------------------------------------------------
__global__ void prep_kernel(const float* __restrict__ A,
                            const float* __restrict__ Bm,
                            unsigned short* __restrict__ A_bf,
                            unsigned short* __restrict__ Bt) {
    int i = blockIdx.x * 256 + threadIdx.x;
    if (i < CDIM * DDIM) {
        A_bf[i] = f2bf(A[i]);
    } else {
        int j = i - CDIM * DDIM;           // j = o*128 + c
        int o = j >> 7, c = j & 127;
        int e = c >> 4, r = c & 15;
        Bt[j] = f2bf(Bm[((size_t)e * ODIM + o) * 16 + r]);
    }
}

// ---------------------------------------------------------------------------
// g1f: fused router + gemm1 + gates + combine. Barrier-free main loop.
//   Mg[n][c] = bf16( (x bf16 @ A^T)[n][c] * gate[n][c>>4] * 0.5 )
// BM=32, BK=32, full K=4096 (128 iters). grid 512, 256 thr (4 indep waves).
// Wave wv: rows (wv&1)*16..+15, col frags (wv>>1)*4..+3. Fragment loads go
// straight from global: lane reads x[row=r15][k=q*8..+8] (fp32->bf16) and
// A_bf[c=f*16+r15][same k]. Waves 0,1 also accumulate fp32 router logits
// from the same x registers (each row covered exactly once). Waves 2,3 read
// the same x rows ~concurrently -> L2 hits. One __syncthreads at epilogue.
// ---------------------------------------------------------------------------
__global__ __launch_bounds__(256, 2) void g1f_kernel(const float* __restrict__ x,
                                                     const unsigned short* __restrict__ A_bf,
                                                     const float* __restrict__ rw,
                                                     const float* __restrict__ rbias,
                                                     unsigned short* __restrict__ Mg) {
    __shared__ float gateLds[32][NEXP];

    int tid  = threadIdx.x;
    int wv   = tid >> 6, lane = tid & 63;
    int r15  = lane & 15, q = lane >> 4;       // frag row / k-quadrant
    int row0 = blockIdx.x * 32;
    int rhalf = wv & 1;
    int fbase = (wv >> 1) * 4;
    int row  = row0 + rhalf * 16 + r15;

    const float* xp = x + (size_t)row * DDIM + q * 8;
    const unsigned short* ap0 = A_bf + (size_t)((fbase + 0) * 16 + r15) * DDIM + q * 8;
    const unsigned short* ap1 = A_bf + (size_t)((fbase + 1) * 16 + r15) * DDIM + q * 8;
    const unsigned short* ap2 = A_bf + (size_t)((fbase + 2) * 16 + r15) * DDIM + q * 8;
    const unsigned short* ap3 = A_bf + (size_t)((fbase + 3) * 16 + r15) * DDIM + q * 8;
    const float* rp = rw + q * 8;

    f32x4 acc[4];
    #pragma unroll
    for (int f = 0; f < 4; f++) acc[f] = (f32x4){0.f, 0.f, 0.f, 0.f};
    float racc[NEXP];
    #pragma unroll
    for (int e = 0; e < NEXP; e++) racc[e] = 0.f;

    // prefetch tile 0
    float4 xa = *(const float4*)xp;
    float4 xb = *(const float4*)(xp + 4);
    bf16x8 af0 = *(const bf16x8*)ap0;
    bf16x8 af1 = *(const bf16x8*)ap1;
    bf16x8 af2 = *(const bf16x8*)ap2;
    bf16x8 af3 = *(const bf16x8*)ap3;

    for (int it = 0; it < 128; ++it) {
        // issue next-tile loads (no barrier anywhere -> stays in flight)
        float4 nxa, nxb; bf16x8 n0, n1, n2, n3;
        if (it < 127) {
            xp += 32; ap0 += 32; ap1 += 32; ap2 += 32; ap3 += 32;
            nxa = *(const float4*)xp;
            nxb = *(const float4*)(xp + 4);
            n0 = *(const bf16x8*)ap0;
            n1 = *(const bf16x8*)ap1;
            n2 = *(const bf16x8*)ap2;
            n3 = *(const bf16x8*)ap3;
        }
        // fp32 router on the register copy of x (waves 0,1 only; each row once)
        if (wv < 2) {
            #pragma unroll
            for (int e = 0; e < NEXP; e++) {
                const float* rpe = rp + (size_t)e * DDIM;
                float4 wa = *(const float4*)(rpe);
                float4 wb = *(const float4*)(rpe + 4);
                racc[e] += xa.x * wa.x + xa.y * wa.y + xa.z * wa.z + xa.w * wa.w
                         + xb.x * wb.x + xb.y * wb.y + xb.z * wb.z + xb.w * wb.w;
            }
            rp += 32;
        }
        // x fragment: fp32 -> bf16 (RNE, same values as the LDS version)
        bf16x8 a;
        a[0] = (__bf16)xa.x; a[1] = (__bf16)xa.y; a[2] = (__bf16)xa.z; a[3] = (__bf16)xa.w;
        a[4] = (__bf16)xb.x; a[5] = (__bf16)xb.y; a[6] = (__bf16)xb.z; a[7] = (__bf16)xb.w;

        acc[0] = __builtin_amdgcn_mfma_f32_16x16x32_bf16(a, af0, acc[0], 0, 0, 0);
        acc[1] = __builtin_amdgcn_mfma_f32_16x16x32_bf16(a, af1, acc[1], 0, 0, 0);
        acc[2] = __builtin_amdgcn_mfma_f32_16x16x32_bf16(a, af2, acc[2], 0, 0, 0);
        acc[3] = __builtin_amdgcn_mfma_f32_16x16x32_bf16(a, af3, acc[3], 0, 0, 0);

        if (it < 127) {
            xa = nxa; xb = nxb;
            af0 = n0; af1 = n1; af2 = n2; af3 = n3;
        }
    }

    // --- router epilogue -----------------------------------------------------
    if (wv < 2) {
        // lanes {r15, r15+16, r15+32, r15+48} hold k-quadrant partials of row r15
        #pragma unroll
        for (int e = 0; e < NEXP; e++) {
            float v = racc[e];
            v += __shfl_xor(v, 16, 64);
            v += __shfl_xor(v, 32, 64);
            racc[e] = v + rbias[e];
        }
        int a1 = 0; float m1 = racc[0];
        #pragma unroll
        for (int e = 1; e < NEXP; e++) if (racc[e] > m1) { m1 = racc[e]; a1 = e; }
        int a2 = -1; float m2 = -3.0e38f;
        #pragma unroll
        for (int e = 0; e < NEXP; e++) if (e != a1 && racc[e] > m2) { m2 = racc[e]; a2 = e; }
        float g1v = 1.f / (1.f + expf(m2 - m1));
        float g2v = 1.f - g1v;
        if (q == 0) {
            #pragma unroll
            for (int e = 0; e < NEXP; e++)
                gateLds[rhalf * 16 + r15][e] =
                    (e == a1) ? g1v * 0.5f : ((e == a2) ? g2v * 0.5f : 0.f);
        }
    }
    __syncthreads();

    // --- gated bf16 write of Mg ---------------------------------------------
    int rowb = rhalf * 16 + q * 4;
    #pragma unroll
    for (int f = 0; f < 4; f++) {
        int e = fbase + f;
        #pragma unroll
        for (int r = 0; r < 4; r++) {
            float g = gateLds[rowb + r][e];
            Mg[(size_t)(row0 + rowb + r) * CDIM + e * 16 + r15] = f2bf(acc[f][r] * g);
        }
    }
}

// ---------------------------------------------------------------------------
// gemm2: out[n][o] = sum_c Mg[n][c] * Bt[o][c]   (K=128, single shot)
// BM=64, BN=128 -> grid 8192 (256 row-blocks x 32 col-blocks), 256 threads.
// LDS 51 KB -> 3 blocks/CU.
// ---------------------------------------------------------------------------
__global__ __launch_bounds__(256, 3) void g2_kernel(const unsigned short* __restrict__ Mg,
                                                    const unsigned short* __restrict__ Bt,
                                                    float* __restrict__ out) {
    __shared__ alignas(16) unsigned short mt[64 * 136];    // [row][128+8]
    __shared__ alignas(16) unsigned short bt[128 * 136];

    int tid = threadIdx.x, wv = tid >> 6, lane = tid & 63;
    int cb = blockIdx.x & 31, rb = blockIdx.x >> 5;
    int row0 = rb * 64, col0 = cb * 128;

    {   // stage M tile: 64 x 128 bf16 = 16 KB, 64 B/thread
        int r = tid >> 2, qq = tid & 3;
        const uint4* src = (const uint4*)(Mg + (size_t)(row0 + r) * CDIM + qq * 32);
        uint4 v0 = src[0], v1 = src[1], v2 = src[2], v3 = src[3];
        uint4* dst = (uint4*)(&mt[r * 136 + qq * 32]);
        dst[0] = v0; dst[1] = v1; dst[2] = v2; dst[3] = v3;
    }
    {   // stage B tile: 128 x 128 bf16 = 32 KB, 128 B/thread
        int o = tid >> 1, h = tid & 1;
        const uint4* src = (const uint4*)(Bt + (size_t)(col0 + o) * CDIM + h * 64);
        uint4 v0 = src[0], v1 = src[1], v2 = src[2], v3 = src[3];
        uint4 v4 = src[4], v5 = src[5], v6 = src[6], v7 = src[7];
        uint4* dst = (uint4*)(&bt[o * 136 + h * 64]);
        dst[0] = v0; dst[1] = v1; dst[2] = v2; dst[3] = v3;
        dst[4] = v4; dst[5] = v5; dst[6] = v6; dst[7] = v7;
    }
    __syncthreads();

    f32x4 acc[8];
    #pragma unroll
    for (int f = 0; f < 8; f++) acc[f] = (f32x4){0.f, 0.f, 0.f, 0.f};

    int mrow = (wv * 16 + (lane & 15)) * 136;
    int kq = (lane >> 4) * 8;
    #pragma unroll
    for (int kk = 0; kk < 4; kk++) {
        bf16x8 a = *(bf16x8*)(&mt[mrow + kk * 32 + kq]);
        #pragma unroll
        for (int f = 0; f < 8; f++) {
            bf16x8 b = *(bf16x8*)(&bt[(f * 16 + (lane & 15)) * 136 + kk * 32 + kq]);
            acc[f] = __builtin_amdgcn_mfma_f32_16x16x32_bf16(a, b, acc[f], 0, 0, 0);
        }
    }

    int rbase = row0 + wv * 16 + (lane >> 4) * 4;
    int cl = lane & 15;
    #pragma unroll
    for (int f = 0; f < 8; f++)
        #pragma unroll
        for (int r = 0; r < 4; r++)
            out[(size_t)(rbase + r) * ODIM + col0 + f * 16 + cl] = acc[f][r];
}

// ---------------------------------------------------------------------------
extern "C" void kernel_launch(void* const* d_in, const int* in_sizes, int n_in,
                              void* d_out, int out_size, void* d_ws, size_t ws_size,
                              hipStream_t stream) {
    const float* x    = (const float*)d_in[0];
    const float* rw   = (const float*)d_in[1];
    const float* rbia = (const float*)d_in[2];
    const float* A    = (const float*)d_in[3];
    const float* Bm   = (const float*)d_in[4];
    float* out = (float*)d_out;

    char* ws = (char*)d_ws;
    unsigned short* A_bf = (unsigned short*)(ws);                 // 1 MB
    unsigned short* Bt   = (unsigned short*)(ws + (1u << 20));    // 1 MB
    unsigned short* Mg   = (unsigned short*)(ws + (2u << 20));    // 4 MB

    prep_kernel<<<4096, 256, 0, stream>>>(A, Bm, A_bf, Bt);
    g1f_kernel <<< 512, 256, 0, stream>>>(x, A_bf, rw, rbia, Mg);
    g2_kernel  <<<8192, 256, 0, stream>>>(Mg, Bt, out);
}

// Round 5
// 550.557 us; speedup vs baseline: 1.1981x; 1.1981x over previous
//
#include <hip/hip_runtime.h>

// ---------------------------------------------------------------------------
// SparseLoRAMoE: out = (gate ⊙ (x @ A_flat^T)) @ Bflat * 0.5
//   N=16384 tokens, D=4096, E=8 experts, R=16, C=E*R=128, O=4096, TOP_K=2
// Round 5: BK=128 drain-amortization WITHOUT R4's register double-buffer
// (R4 failed absmax 0.119; its only novel mechanism was the npx/npa
// double-buffer + adv trick -> removed). Single tile in flight, hand-named
// registers, R2's verified thread maps and two-barrier sync structure.
// Per big-iter: [if(it) bar] [12 coalesced loads] [router FMA overlaps the
// load wait] [convert] [LDS stores] [bar] [4 k-subtiles of ds_read+MFMA].
// Drain paid once per 128-k instead of once per 32-k (4x amortization).
// ---------------------------------------------------------------------------

#define NTOK   16384
#define DDIM   4096
#define NEXP   8
#define CDIM   128     // E*R
#define ODIM   4096

typedef float  f32x4  __attribute__((ext_vector_type(4)));
typedef __bf16 bf16x8 __attribute__((ext_vector_type(8)));

__device__ __forceinline__ unsigned short f2bf(float f) {
    union { float f; unsigned u; } v; v.f = f;
    unsigned r = v.u + 0x7FFFu + ((v.u >> 16) & 1u);   // RNE
    return (unsigned short)(r >> 16);
}

// ---------------------------------------------------------------------------
// prep: A [128,4096] fp32 -> bf16 (same layout); Bm [8,4096,16] fp32 ->
//       Bt [o=4096][c=128] bf16 (o-major, c contiguous)
// grid 4096 x 256
// ---------------------------------------------------------------------------
__global__ void prep_kernel(const float* __restrict__ A,
                            const float* __restrict__ Bm,
                            unsigned short* __restrict__ A_bf,
                            unsigned short* __restrict__ Bt) {
    int i = blockIdx.x * 256 + threadIdx.x;
    if (i < CDIM * DDIM) {
        A_bf[i] = f2bf(A[i]);
    } else {
        int j = i - CDIM * DDIM;           // j = o*128 + c
        int o = j >> 7, c = j & 127;
        int e = c >> 4, r = c & 15;
        Bt[j] = f2bf(Bm[((size_t)e * ODIM + o) * 16 + r]);
    }
}

// ---------------------------------------------------------------------------
// g1f: fused router + gemm1 + gates + combine. BK=128 per barrier pair,
// single tile in flight (no register double-buffer).
//   Mg[n][c] = bf16( (x bf16 @ A^T)[n][c] * gate[n][c>>4] * 0.5 )
// BM=32, 32 big-iters of 128 k. grid 512 (2 blocks/CU), 256 thr (4 waves).
// Thread maps identical to R2 (verified): x row sr=tid>>3, 4 floats at
// sq*4 (+32 per subtile); A row ac=tid>>1, 16 bf16 at ah*16 (+32/subtile).
// Wave wv: rows (wv&1)*16..+15, col frags (wv>>1)*4..+3.
// ---------------------------------------------------------------------------
__global__ __launch_bounds__(256, 2) void g1f_kernel(const float* __restrict__ x,
                                                     const unsigned short* __restrict__ A_bf,
                                                     const float* __restrict__ rw,
                                                     const float* __restrict__ rbias,
                                                     unsigned short* __restrict__ Mg) {
    __shared__ alignas(16) unsigned short xt[32 * 136];    // [row][128+8 pad]
    __shared__ alignas(16) unsigned short at[128 * 136];
    __shared__ float gateLds[32][NEXP];

    int tid = threadIdx.x;
    int wv = tid >> 6, lane = tid & 63;
    int r15 = lane & 15, q = lane >> 4;
    int row0 = blockIdx.x * 32;
    int rhalf = wv & 1;
    int fbase = (wv >> 1) * 4;

    int sr = tid >> 3, sq = tid & 7;
    const float* xsrc = x + (size_t)(row0 + sr) * DDIM + sq * 4;
    int ac = tid >> 1, ah = tid & 1;
    const unsigned short* asrc = A_bf + (size_t)ac * DDIM + ah * 16;
    const float* rsrc = rw + sq * 4;

    int xoff = sr * 136 + sq * 4;
    int aoff = ac * 136 + ah * 16;

    f32x4 acc0 = (f32x4){0.f, 0.f, 0.f, 0.f};
    f32x4 acc1 = (f32x4){0.f, 0.f, 0.f, 0.f};
    f32x4 acc2 = (f32x4){0.f, 0.f, 0.f, 0.f};
    f32x4 acc3 = (f32x4){0.f, 0.f, 0.f, 0.f};
    float racc[NEXP];
    #pragma unroll
    for (int e = 0; e < NEXP; e++) racc[e] = 0.f;

    for (int it = 0; it < 32; ++it) {
        // ---- issue tile-it loads: 4x float4 (x), 8x uint4 (A) ------------
        float4 px0 = *(const float4*)(xsrc);
        float4 px1 = *(const float4*)(xsrc + 32);
        float4 px2 = *(const float4*)(xsrc + 64);
        float4 px3 = *(const float4*)(xsrc + 96);
        uint4 pa00 = *(const uint4*)(asrc);
        uint4 pa01 = *(const uint4*)(asrc + 8);
        uint4 pa10 = *(const uint4*)(asrc + 32);
        uint4 pa11 = *(const uint4*)(asrc + 40);
        uint4 pa20 = *(const uint4*)(asrc + 64);
        uint4 pa21 = *(const uint4*)(asrc + 72);
        uint4 pa30 = *(const uint4*)(asrc + 96);
        uint4 pa31 = *(const uint4*)(asrc + 104);

        // ---- router FMA on x regs (independent work during load wait) ----
        #pragma unroll
        for (int e = 0; e < NEXP; e++) {
            const float* rpe = rsrc + (size_t)e * DDIM;
            float4 w0 = *(const float4*)(rpe);
            float4 w1 = *(const float4*)(rpe + 32);
            float4 w2 = *(const float4*)(rpe + 64);
            float4 w3 = *(const float4*)(rpe + 96);
            racc[e] += px0.x * w0.x + px0.y * w0.y + px0.z * w0.z + px0.w * w0.w
                     + px1.x * w1.x + px1.y * w1.y + px1.z * w1.z + px1.w * w1.w
                     + px2.x * w2.x + px2.y * w2.y + px2.z * w2.z + px2.w * w2.w
                     + px3.x * w3.x + px3.y * w3.y + px3.z * w3.z + px3.w * w3.w;
        }

        // ---- convert x to bf16 (RNE) -------------------------------------
        ushort4 xw0, xw1, xw2, xw3;
        xw0.x = f2bf(px0.x); xw0.y = f2bf(px0.y); xw0.z = f2bf(px0.z); xw0.w = f2bf(px0.w);
        xw1.x = f2bf(px1.x); xw1.y = f2bf(px1.y); xw1.z = f2bf(px1.z); xw1.w = f2bf(px1.w);
        xw2.x = f2bf(px2.x); xw2.y = f2bf(px2.y); xw2.z = f2bf(px2.z); xw2.w = f2bf(px2.w);
        xw3.x = f2bf(px3.x); xw3.y = f2bf(px3.y); xw3.z = f2bf(px3.z); xw3.w = f2bf(px3.w);

        if (it) __syncthreads();           // WAR: previous tile's readers done
        *(ushort4*)(&xt[xoff      ]) = xw0;
        *(ushort4*)(&xt[xoff + 32 ]) = xw1;
        *(ushort4*)(&xt[xoff + 64 ]) = xw2;
        *(ushort4*)(&xt[xoff + 96 ]) = xw3;
        *(uint4*)(&at[aoff      ]) = pa00;  *(uint4*)(&at[aoff + 8  ]) = pa01;
        *(uint4*)(&at[aoff + 32 ]) = pa10;  *(uint4*)(&at[aoff + 40 ]) = pa11;
        *(uint4*)(&at[aoff + 64 ]) = pa20;  *(uint4*)(&at[aoff + 72 ]) = pa21;
        *(uint4*)(&at[aoff + 96 ]) = pa30;  *(uint4*)(&at[aoff + 104]) = pa31;
        __syncthreads();                   // RAW: staging visible

        // ---- 4 k-subtiles of MFMA ---------------------------------------
        #pragma unroll
        for (int kk = 0; kk < 4; kk++) {
            bf16x8 a = *(bf16x8*)(&xt[(rhalf * 16 + r15) * 136 + kk * 32 + q * 8]);
            bf16x8 b0 = *(bf16x8*)(&at[((fbase + 0) * 16 + r15) * 136 + kk * 32 + q * 8]);
            bf16x8 b1 = *(bf16x8*)(&at[((fbase + 1) * 16 + r15) * 136 + kk * 32 + q * 8]);
            bf16x8 b2 = *(bf16x8*)(&at[((fbase + 2) * 16 + r15) * 136 + kk * 32 + q * 8]);
            bf16x8 b3 = *(bf16x8*)(&at[((fbase + 3) * 16 + r15) * 136 + kk * 32 + q * 8]);
            acc0 = __builtin_amdgcn_mfma_f32_16x16x32_bf16(a, b0, acc0, 0, 0, 0);
            acc1 = __builtin_amdgcn_mfma_f32_16x16x32_bf16(a, b1, acc1, 0, 0, 0);
            acc2 = __builtin_amdgcn_mfma_f32_16x16x32_bf16(a, b2, acc2, 0, 0, 0);
            acc3 = __builtin_amdgcn_mfma_f32_16x16x32_bf16(a, b3, acc3, 0, 0, 0);
        }

        xsrc += 128; asrc += 128; rsrc += 128;
    }

    // --- router epilogue: reduce 8 k-lanes (sq = lane bits 0..2) -----------
    #pragma unroll
    for (int e = 0; e < NEXP; e++) {
        float v = racc[e];
        v += __shfl_xor(v, 1, 64);
        v += __shfl_xor(v, 2, 64);
        v += __shfl_xor(v, 4, 64);
        racc[e] = v + rbias[e];
    }
    int a1 = 0; float m1 = racc[0];
    #pragma unroll
    for (int e = 1; e < NEXP; e++) if (racc[e] > m1) { m1 = racc[e]; a1 = e; }
    int a2 = -1; float m2 = -3.0e38f;
    #pragma unroll
    for (int e = 0; e < NEXP; e++) if (e != a1 && racc[e] > m2) { m2 = racc[e]; a2 = e; }
    float g1v = 1.f / (1.f + expf(m2 - m1));
    float g2v = 1.f - g1v;
    if ((tid & 7) == 0) {
        #pragma unroll
        for (int e = 0; e < NEXP; e++)
            gateLds[sr][e] = (e == a1) ? g1v * 0.5f : ((e == a2) ? g2v * 0.5f : 0.f);
    }
    __syncthreads();

    // --- gated bf16 write of Mg ---------------------------------------------
    int rowb = rhalf * 16 + q * 4;
    f32x4 accv[4] = {acc0, acc1, acc2, acc3};
    #pragma unroll
    for (int f = 0; f < 4; f++) {
        int e = fbase + f;
        #pragma unroll
        for (int r = 0; r < 4; r++) {
            float g = gateLds[rowb + r][e];
            Mg[(size_t)(row0 + rowb + r) * CDIM + e * 16 + r15] = f2bf(accv[f][r] * g);
        }
    }
}

// ---------------------------------------------------------------------------
// gemm2: out[n][o] = sum_c Mg[n][c] * Bt[o][c]   (K=128, single shot)
// BM=64, BN=128 -> grid 8192 (256 row-blocks x 32 col-blocks), 256 threads.
// LDS 51 KB -> 3 blocks/CU.
// ---------------------------------------------------------------------------
__global__ __launch_bounds__(256, 3) void g2_kernel(const unsigned short* __restrict__ Mg,
                                                    const unsigned short* __restrict__ Bt,
                                                    float* __restrict__ out) {
    __shared__ alignas(16) unsigned short mt[64 * 136];    // [row][128+8]
    __shared__ alignas(16) unsigned short bt[128 * 136];

    int tid = threadIdx.x, wv = tid >> 6, lane = tid & 63;
    int cb = blockIdx.x & 31, rb = blockIdx.x >> 5;
    int row0 = rb * 64, col0 = cb * 128;

    {   // stage M tile: 64 x 128 bf16 = 16 KB, 64 B/thread
        int r = tid >> 2, qq = tid & 3;
        const uint4* src = (const uint4*)(Mg + (size_t)(row0 + r) * CDIM + qq * 32);
        uint4 v0 = src[0], v1 = src[1], v2 = src[2], v3 = src[3];
        uint4* dst = (uint4*)(&mt[r * 136 + qq * 32]);
        dst[0] = v0; dst[1] = v1; dst[2] = v2; dst[3] = v3;
    }
    {   // stage B tile: 128 x 128 bf16 = 32 KB, 128 B/thread
        int o = tid >> 1, h = tid & 1;
        const uint4* src = (const uint4*)(Bt + (size_t)(col0 + o) * CDIM + h * 64);
        uint4 v0 = src[0], v1 = src[1], v2 = src[2], v3 = src[3];
        uint4 v4 = src[4], v5 = src[5], v6 = src[6], v7 = src[7];
        uint4* dst = (uint4*)(&bt[o * 136 + h * 64]);
        dst[0] = v0; dst[1] = v1; dst[2] = v2; dst[3] = v3;
        dst[4] = v4; dst[5] = v5; dst[6] = v6; dst[7] = v7;
    }
    __syncthreads();

    f32x4 acc[8];
    #pragma unroll
    for (int f = 0; f < 8; f++) acc[f] = (f32x4){0.f, 0.f, 0.f, 0.f};

    int mrow = (wv * 16 + (lane & 15)) * 136;
    int kq = (lane >> 4) * 8;
    #pragma unroll
    for (int kk = 0; kk < 4; kk++) {
        bf16x8 a = *(bf16x8*)(&mt[mrow + kk * 32 + kq]);
        #pragma unroll
        for (int f = 0; f < 8; f++) {
            bf16x8 b = *(bf16x8*)(&bt[(f * 16 + (lane & 15)) * 136 + kk * 32 + kq]);
            acc[f] = __builtin_amdgcn_mfma_f32_16x16x32_bf16(a, b, acc[f], 0, 0, 0);
        }
    }

    int rbase = row0 + wv * 16 + (lane >> 4) * 4;
    int cl = lane & 15;
    #pragma unroll
    for (int f = 0; f < 8; f++)
        #pragma unroll
        for (int r = 0; r < 4; r++)
            out[(size_t)(rbase + r) * ODIM + col0 + f * 16 + cl] = acc[f][r];
}

// ---------------------------------------------------------------------------
extern "C" void kernel_launch(void* const* d_in, const int* in_sizes, int n_in,
                              void* d_out, int out_size, void* d_ws, size_t ws_size,
                              hipStream_t stream) {
    const float* x    = (const float*)d_in[0];
    const float* rw   = (const float*)d_in[1];
    const float* rbia = (const float*)d_in[2];
    const float* A    = (const float*)d_in[3];
    const float* Bm   = (const float*)d_in[4];
    float* out = (float*)d_out;

    char* ws = (char*)d_ws;
    unsigned short* A_bf = (unsigned short*)(ws);                 // 1 MB
    unsigned short* Bt   = (unsigned short*)(ws + (1u << 20));    // 1 MB
    unsigned short* Mg   = (unsigned short*)(ws + (2u << 20));    // 4 MB

    prep_kernel<<<4096, 256, 0, stream>>>(A, Bm, A_bf, Bt);
    g1f_kernel <<< 512, 256, 0, stream>>>(x, A_bf, rw, rbia, Mg);
    g2_kernel  <<<8192, 256, 0, stream>>>(Mg, Bt, out);
}

// Round 6
// 538.671 us; speedup vs baseline: 1.2246x; 1.0221x over previous
//
#include <hip/hip_runtime.h>

// ---------------------------------------------------------------------------
// SparseLoRAMoE: out = (gate ⊙ (x @ A_flat^T)) @ Bflat * 0.5
//   N=16384 tokens, D=4096, E=8 experts, R=16, C=E*R=128, O=4096, TOP_K=2
// Round 6: fix the REAL bottleneck — vector-memory line-scatter.
//   Evidence: g1f 186us invariant to barrier structure (R2 vs R5) AND to
//   memory residency (L3-warm replays identical) -> TA/L1 line-rate bound.
//   A staging read rows 8KB apart: 64 distinct cache lines per wave-load.
//   Fix: prep retiles A -> A2[kt][c][k'] so each 32KB A-tile is contiguous;
//   g1f/g2 stage all tiles with lane-adjacent 16B loads (coalesced fast
//   path). LDS contents/maps/numerics identical to R5 (passed).
// ---------------------------------------------------------------------------

#define NTOK   16384
#define DDIM   4096
#define NEXP   8
#define CDIM   128     // E*R
#define ODIM   4096

typedef float  f32x4  __attribute__((ext_vector_type(4)));
typedef __bf16 bf16x8 __attribute__((ext_vector_type(8)));

__device__ __forceinline__ unsigned short f2bf(float f) {
    union { float f; unsigned u; } v; v.f = f;
    unsigned r = v.u + 0x7FFFu + ((v.u >> 16) & 1u);   // RNE
    return (unsigned short)(r >> 16);
}

// ---------------------------------------------------------------------------
// prep: A [c=128][k=4096] fp32 -> A2 bf16 tiled [kt=32][c=128][k'=128]
//       (each 128-k tile contiguous 32 KB); Bm [8,4096,16] fp32 ->
//       Bt [o=4096][c=128] bf16 (o-major, c contiguous -> 128-row tiles
//       are contiguous 32 KB slabs).
// grid 4096 x 256
// ---------------------------------------------------------------------------
__global__ void prep_kernel(const float* __restrict__ A,
                            const float* __restrict__ Bm,
                            unsigned short* __restrict__ A2,
                            unsigned short* __restrict__ Bt) {
    int i = blockIdx.x * 256 + threadIdx.x;
    if (i < CDIM * DDIM) {
        int c = i >> 12, k = i & 4095;
        A2[(size_t)(k >> 7) * (CDIM * 128) + c * 128 + (k & 127)] = f2bf(A[i]);
    } else {
        int j = i - CDIM * DDIM;           // j = o*128 + c
        int o = j >> 7, c = j & 127;
        int e = c >> 4, r = c & 15;
        Bt[j] = f2bf(Bm[((size_t)e * ODIM + o) * 16 + r]);
    }
}

// ---------------------------------------------------------------------------
// g1f: fused router + gemm1 + gates + combine. BK=128 per barrier pair.
//   Mg[n][c] = bf16( (x bf16 @ A^T)[n][c] * gate[n][c>>4] * 0.5 )
// BM=32, 32 big-iters of 128 k. grid 512 (2 blocks/CU), 256 thr (4 waves).
// A staging now reads the contiguous A2 tile: lane-adjacent 16B (coalesced);
// LDS write at[(j*16 + tid>>4)][ (tid&15)*8 ] -> same padded [c][k'] tile
// contents as R5. x staging / router / MFMA / epilogue identical to R5.
// ---------------------------------------------------------------------------
__global__ __launch_bounds__(256, 2) void g1f_kernel(const float* __restrict__ x,
                                                     const unsigned short* __restrict__ A2,
                                                     const float* __restrict__ rw,
                                                     const float* __restrict__ rbias,
                                                     unsigned short* __restrict__ Mg) {
    __shared__ alignas(16) unsigned short xt[32 * 136];    // [row][128+8 pad]
    __shared__ alignas(16) unsigned short at[128 * 136];   // [c][128+8 pad]
    __shared__ float gateLds[32][NEXP];

    int tid = threadIdx.x;
    int wv = tid >> 6, lane = tid & 63;
    int r15 = lane & 15, q = lane >> 4;
    int row0 = blockIdx.x * 32;
    int rhalf = wv & 1;
    int fbase = (wv >> 1) * 4;

    int sr = tid >> 3, sq = tid & 7;
    const float* xsrc = x + (size_t)(row0 + sr) * DDIM + sq * 4;
    const unsigned short* asrc = A2 + (size_t)tid * 8;   // coalesced tile base
    const float* rsrc = rw + sq * 4;

    int xoff = sr * 136 + sq * 4;
    int aoff = (tid >> 4) * 136 + (tid & 15) * 8;        // j adds 16*136

    f32x4 acc0 = (f32x4){0.f, 0.f, 0.f, 0.f};
    f32x4 acc1 = (f32x4){0.f, 0.f, 0.f, 0.f};
    f32x4 acc2 = (f32x4){0.f, 0.f, 0.f, 0.f};
    f32x4 acc3 = (f32x4){0.f, 0.f, 0.f, 0.f};
    float racc[NEXP];
    #pragma unroll
    for (int e = 0; e < NEXP; e++) racc[e] = 0.f;

    for (int it = 0; it < 32; ++it) {
        // ---- issue tile-it loads: x 4x float4; A 8x uint4 (all coalesced) --
        float4 px0 = *(const float4*)(xsrc);
        float4 px1 = *(const float4*)(xsrc + 32);
        float4 px2 = *(const float4*)(xsrc + 64);
        float4 px3 = *(const float4*)(xsrc + 96);
        uint4 pa0 = *(const uint4*)(asrc);
        uint4 pa1 = *(const uint4*)(asrc + 2048);
        uint4 pa2 = *(const uint4*)(asrc + 2 * 2048);
        uint4 pa3 = *(const uint4*)(asrc + 3 * 2048);
        uint4 pa4 = *(const uint4*)(asrc + 4 * 2048);
        uint4 pa5 = *(const uint4*)(asrc + 5 * 2048);
        uint4 pa6 = *(const uint4*)(asrc + 6 * 2048);
        uint4 pa7 = *(const uint4*)(asrc + 7 * 2048);

        // ---- router FMA on x regs (independent work during load wait) ----
        #pragma unroll
        for (int e = 0; e < NEXP; e++) {
            const float* rpe = rsrc + (size_t)e * DDIM;
            float4 w0 = *(const float4*)(rpe);
            float4 w1 = *(const float4*)(rpe + 32);
            float4 w2 = *(const float4*)(rpe + 64);
            float4 w3 = *(const float4*)(rpe + 96);
            racc[e] += px0.x * w0.x + px0.y * w0.y + px0.z * w0.z + px0.w * w0.w
                     + px1.x * w1.x + px1.y * w1.y + px1.z * w1.z + px1.w * w1.w
                     + px2.x * w2.x + px2.y * w2.y + px2.z * w2.z + px2.w * w2.w
                     + px3.x * w3.x + px3.y * w3.y + px3.z * w3.z + px3.w * w3.w;
        }

        // ---- convert x to bf16 (RNE) -------------------------------------
        ushort4 xw0, xw1, xw2, xw3;
        xw0.x = f2bf(px0.x); xw0.y = f2bf(px0.y); xw0.z = f2bf(px0.z); xw0.w = f2bf(px0.w);
        xw1.x = f2bf(px1.x); xw1.y = f2bf(px1.y); xw1.z = f2bf(px1.z); xw1.w = f2bf(px1.w);
        xw2.x = f2bf(px2.x); xw2.y = f2bf(px2.y); xw2.z = f2bf(px2.z); xw2.w = f2bf(px2.w);
        xw3.x = f2bf(px3.x); xw3.y = f2bf(px3.y); xw3.z = f2bf(px3.z); xw3.w = f2bf(px3.w);

        if (it) __syncthreads();           // WAR: previous tile's readers done
        *(ushort4*)(&xt[xoff      ]) = xw0;
        *(ushort4*)(&xt[xoff + 32 ]) = xw1;
        *(ushort4*)(&xt[xoff + 64 ]) = xw2;
        *(ushort4*)(&xt[xoff + 96 ]) = xw3;
        *(uint4*)(&at[aoff           ]) = pa0;
        *(uint4*)(&at[aoff + 1 * 2176]) = pa1;   // 2176 = 16 rows * 136
        *(uint4*)(&at[aoff + 2 * 2176]) = pa2;
        *(uint4*)(&at[aoff + 3 * 2176]) = pa3;
        *(uint4*)(&at[aoff + 4 * 2176]) = pa4;
        *(uint4*)(&at[aoff + 5 * 2176]) = pa5;
        *(uint4*)(&at[aoff + 6 * 2176]) = pa6;
        *(uint4*)(&at[aoff + 7 * 2176]) = pa7;
        __syncthreads();                   // RAW: staging visible

        // ---- 4 k-subtiles of MFMA ---------------------------------------
        #pragma unroll
        for (int kk = 0; kk < 4; kk++) {
            bf16x8 a = *(bf16x8*)(&xt[(rhalf * 16 + r15) * 136 + kk * 32 + q * 8]);
            bf16x8 b0 = *(bf16x8*)(&at[((fbase + 0) * 16 + r15) * 136 + kk * 32 + q * 8]);
            bf16x8 b1 = *(bf16x8*)(&at[((fbase + 1) * 16 + r15) * 136 + kk * 32 + q * 8]);
            bf16x8 b2 = *(bf16x8*)(&at[((fbase + 2) * 16 + r15) * 136 + kk * 32 + q * 8]);
            bf16x8 b3 = *(bf16x8*)(&at[((fbase + 3) * 16 + r15) * 136 + kk * 32 + q * 8]);
            acc0 = __builtin_amdgcn_mfma_f32_16x16x32_bf16(a, b0, acc0, 0, 0, 0);
            acc1 = __builtin_amdgcn_mfma_f32_16x16x32_bf16(a, b1, acc1, 0, 0, 0);
            acc2 = __builtin_amdgcn_mfma_f32_16x16x32_bf16(a, b2, acc2, 0, 0, 0);
            acc3 = __builtin_amdgcn_mfma_f32_16x16x32_bf16(a, b3, acc3, 0, 0, 0);
        }

        xsrc += 128; asrc += CDIM * 128; rsrc += 128;
    }

    // --- router epilogue: reduce 8 k-lanes (sq = lane bits 0..2) -----------
    #pragma unroll
    for (int e = 0; e < NEXP; e++) {
        float v = racc[e];
        v += __shfl_xor(v, 1, 64);
        v += __shfl_xor(v, 2, 64);
        v += __shfl_xor(v, 4, 64);
        racc[e] = v + rbias[e];
    }
    int a1 = 0; float m1 = racc[0];
    #pragma unroll
    for (int e = 1; e < NEXP; e++) if (racc[e] > m1) { m1 = racc[e]; a1 = e; }
    int a2 = -1; float m2 = -3.0e38f;
    #pragma unroll
    for (int e = 0; e < NEXP; e++) if (e != a1 && racc[e] > m2) { m2 = racc[e]; a2 = e; }
    float g1v = 1.f / (1.f + expf(m2 - m1));
    float g2v = 1.f - g1v;
    if ((tid & 7) == 0) {
        #pragma unroll
        for (int e = 0; e < NEXP; e++)
            gateLds[sr][e] = (e == a1) ? g1v * 0.5f : ((e == a2) ? g2v * 0.5f : 0.f);
    }
    __syncthreads();

    // --- gated bf16 write of Mg ---------------------------------------------
    int rowb = rhalf * 16 + q * 4;
    f32x4 accv[4] = {acc0, acc1, acc2, acc3};
    #pragma unroll
    for (int f = 0; f < 4; f++) {
        int e = fbase + f;
        #pragma unroll
        for (int r = 0; r < 4; r++) {
            float g = gateLds[rowb + r][e];
            Mg[(size_t)(row0 + rowb + r) * CDIM + e * 16 + r15] = f2bf(accv[f][r] * g);
        }
    }
}

// ---------------------------------------------------------------------------
// gemm2: out[n][o] = sum_c Mg[n][c] * Bt[o][c]   (K=128, single shot)
// BM=64, BN=128 -> grid 8192 (256 row-blocks x 32 col-blocks), 256 threads.
// Both source tiles are contiguous slabs (full-width c) -> staged with
// lane-adjacent 16B coalesced loads. LDS 51 KB -> 3 blocks/CU.
// ---------------------------------------------------------------------------
__global__ __launch_bounds__(256, 3) void g2_kernel(const unsigned short* __restrict__ Mg,
                                                    const unsigned short* __restrict__ Bt,
                                                    float* __restrict__ out) {
    __shared__ alignas(16) unsigned short mt[64 * 136];    // [row][128+8]
    __shared__ alignas(16) unsigned short bt[128 * 136];

    int tid = threadIdx.x, wv = tid >> 6, lane = tid & 63;
    int cb = blockIdx.x & 31, rb = blockIdx.x >> 5;
    int row0 = rb * 64, col0 = cb * 128;

    int soff = (tid >> 4) * 136 + (tid & 15) * 8;          // +16 rows per j
    {   // stage M tile: contiguous 16 KB at Mg+row0*128, 4x uint4/thread
        const unsigned short* src = Mg + (size_t)row0 * CDIM + tid * 8;
        uint4 v0 = *(const uint4*)(src);
        uint4 v1 = *(const uint4*)(src + 2048);
        uint4 v2 = *(const uint4*)(src + 2 * 2048);
        uint4 v3 = *(const uint4*)(src + 3 * 2048);
        *(uint4*)(&mt[soff           ]) = v0;
        *(uint4*)(&mt[soff + 1 * 2176]) = v1;
        *(uint4*)(&mt[soff + 2 * 2176]) = v2;
        *(uint4*)(&mt[soff + 3 * 2176]) = v3;
    }
    {   // stage B tile: contiguous 32 KB at Bt+col0*128, 8x uint4/thread
        const unsigned short* src = Bt + (size_t)col0 * CDIM + tid * 8;
        uint4 v0 = *(const uint4*)(src);
        uint4 v1 = *(const uint4*)(src + 2048);
        uint4 v2 = *(const uint4*)(src + 2 * 2048);
        uint4 v3 = *(const uint4*)(src + 3 * 2048);
        uint4 v4 = *(const uint4*)(src + 4 * 2048);
        uint4 v5 = *(const uint4*)(src + 5 * 2048);
        uint4 v6 = *(const uint4*)(src + 6 * 2048);
        uint4 v7 = *(const uint4*)(src + 7 * 2048);
        *(uint4*)(&bt[soff           ]) = v0;
        *(uint4*)(&bt[soff + 1 * 2176]) = v1;
        *(uint4*)(&bt[soff + 2 * 2176]) = v2;
        *(uint4*)(&bt[soff + 3 * 2176]) = v3;
        *(uint4*)(&bt[soff + 4 * 2176]) = v4;
        *(uint4*)(&bt[soff + 5 * 2176]) = v5;
        *(uint4*)(&bt[soff + 6 * 2176]) = v6;
        *(uint4*)(&bt[soff + 7 * 2176]) = v7;
    }
    __syncthreads();

    f32x4 acc[8];
    #pragma unroll
    for (int f = 0; f < 8; f++) acc[f] = (f32x4){0.f, 0.f, 0.f, 0.f};

    int mrow = (wv * 16 + (lane & 15)) * 136;
    int kq = (lane >> 4) * 8;
    #pragma unroll
    for (int kk = 0; kk < 4; kk++) {
        bf16x8 a = *(bf16x8*)(&mt[mrow + kk * 32 + kq]);
        #pragma unroll
        for (int f = 0; f < 8; f++) {
            bf16x8 b = *(bf16x8*)(&bt[(f * 16 + (lane & 15)) * 136 + kk * 32 + kq]);
            acc[f] = __builtin_amdgcn_mfma_f32_16x16x32_bf16(a, b, acc[f], 0, 0, 0);
        }
    }

    int rbase = row0 + wv * 16 + (lane >> 4) * 4;
    int cl = lane & 15;
    #pragma unroll
    for (int f = 0; f < 8; f++)
        #pragma unroll
        for (int r = 0; r < 4; r++)
            out[(size_t)(rbase + r) * ODIM + col0 + f * 16 + cl] = acc[f][r];
}

// ---------------------------------------------------------------------------
extern "C" void kernel_launch(void* const* d_in, const int* in_sizes, int n_in,
                              void* d_out, int out_size, void* d_ws, size_t ws_size,
                              hipStream_t stream) {
    const float* x    = (const float*)d_in[0];
    const float* rw   = (const float*)d_in[1];
    const float* rbia = (const float*)d_in[2];
    const float* A    = (const float*)d_in[3];
    const float* Bm   = (const float*)d_in[4];
    float* out = (float*)d_out;

    char* ws = (char*)d_ws;
    unsigned short* A2 = (unsigned short*)(ws);                   // 1 MB
    unsigned short* Bt = (unsigned short*)(ws + (1u << 20));      // 1 MB
    unsigned short* Mg = (unsigned short*)(ws + (2u << 20));      // 4 MB

    prep_kernel<<<4096, 256, 0, stream>>>(A, Bm, A2, Bt);
    g1f_kernel <<< 512, 256, 0, stream>>>(x, A2, rw, rbia, Mg);
    g2_kernel  <<<8192, 256, 0, stream>>>(Mg, Bt, out);
}